// Round 1
// baseline (8735.709 us; speedup 1.0000x reference)
//
#include <hip/hip_runtime.h>
#include <math.h>

#define NN 50000
#define NE 800000
#define NG 128
#define DIM 128
#define CLASSES 10

// ---------------- utility kernels ----------------

__global__ void zero_kernel(float* __restrict__ p, int n4) {
    int i = blockIdx.x * blockDim.x + threadIdx.x;
    int stride = gridDim.x * blockDim.x;
    float4 z = make_float4(0.f, 0.f, 0.f, 0.f);
    for (; i < n4; i += stride) ((float4*)p)[i] = z;
}

__global__ void deg_kernel(const int* __restrict__ dst, float* __restrict__ deg, int E) {
    int i = blockIdx.x * blockDim.x + threadIdx.x;
    int stride = gridDim.x * blockDim.x;
    for (; i < E; i += stride) atomicAdd(&deg[dst[i]], 1.0f);
}

__global__ void norm_kernel(float* __restrict__ d, int n) {  // in-place deg -> deg^-0.5
    int i = blockIdx.x * blockDim.x + threadIdx.x;
    if (i < n) {
        float v = d[i];
        v = v < 1.f ? 1.f : v;
        d[i] = 1.0f / sqrtf(v);
    }
}

// agg[dst] += feat[src] * norm[src]; 32 lanes (float4 each) per edge, 8 edges per block-iter
__global__ void hop_kernel(const float* __restrict__ feat, const float* __restrict__ nrm,
                           const int* __restrict__ src, const int* __restrict__ dst,
                           float* __restrict__ agg, int E) {
    int lane = threadIdx.x & 31;
    int esub = threadIdx.x >> 5;
    int stride = gridDim.x * 8;
    for (int e = blockIdx.x * 8 + esub; e < E; e += stride) {
        int s = src[e], d = dst[e];
        float ns = nrm[s];
        float4 v = ((const float4*)(feat + (size_t)s * DIM))[lane];
        float* o = agg + (size_t)d * DIM + lane * 4;
        atomicAdd(o + 0, v.x * ns);
        atomicAdd(o + 1, v.y * ns);
        atomicAdd(o + 2, v.z * ns);
        atomicAdd(o + 3, v.w * ns);
    }
}

// agg *= norm[row]  (n4 = N*DIM/4 float4s)
__global__ void scale_kernel(float* __restrict__ agg, const float* __restrict__ nrm, int n4) {
    int i = blockIdx.x * blockDim.x + threadIdx.x;
    int stride = gridDim.x * blockDim.x;
    for (; i < n4; i += stride) {
        float s = nrm[i >> 5];  // float4 i covers dims [4i,4i+4) of row i/32
        float4 v = ((float4*)agg)[i];
        v.x *= s; v.y *= s; v.z *= s; v.w *= s;
        ((float4*)agg)[i] = v;
    }
}

// ---------------- fp32 GEMM: out[M,128] = relu([A0|A1|A2] @ W + b) ----------------
// block tile 128x128, 256 threads, per-thread 8x8, BK=32; in-place (out==A0) is safe:
// each block reads only its own 128 rows and writes them in the epilogue.

#define BM 128
#define BK 32

__global__ __launch_bounds__(256) void gemm_kernel(
    const float* __restrict__ A0, const float* __restrict__ A1, const float* __restrict__ A2,
    const float* __restrict__ W, const float* __restrict__ bias,
    float* __restrict__ out, int M) {
    __shared__ float As[BK][BM + 4];   // transposed: As[k][row], pad 4 keeps f4 align + spreads banks
    __shared__ float Wt[BK][DIM];

    int tid = threadIdx.x;
    int row0 = blockIdx.x * BM;
    int r0 = (tid >> 4) * 8;   // 16 row-groups
    int c0 = (tid & 15) * 8;   // 16 col-groups

    float acc[8][8];
#pragma unroll
    for (int i = 0; i < 8; i++)
#pragma unroll
        for (int j = 0; j < 8; j++) acc[i][j] = 0.f;

    const float* parts[3] = {A0, A1, A2};
    for (int p = 0; p < 3; ++p) {
        const float* A = parts[p];
        for (int kc = 0; kc < DIM; kc += BK) {
            // stage A tile (128 rows x 32 k), transposed into As
#pragma unroll
            for (int it = 0; it < 4; ++it) {
                int r = (tid >> 3) + 32 * it;
                int k4 = (tid & 7) * 4;
                int grow = row0 + r;
                float4 v = make_float4(0.f, 0.f, 0.f, 0.f);
                if (grow < M) v = *(const float4*)(A + (size_t)grow * DIM + kc + k4);
                As[k4 + 0][r] = v.x;
                As[k4 + 1][r] = v.y;
                As[k4 + 2][r] = v.z;
                As[k4 + 3][r] = v.w;
            }
            // stage W tile (32 k x 128 n)
#pragma unroll
            for (int it = 0; it < 4; ++it) {
                int k = (tid >> 5) + 8 * it;
                int c = (tid & 31) * 4;
                *(float4*)(&Wt[k][c]) = *(const float4*)(W + (size_t)(p * DIM + kc + k) * DIM + c);
            }
            __syncthreads();
#pragma unroll
            for (int kk = 0; kk < BK; ++kk) {
                float4 a0 = *(const float4*)(&As[kk][r0]);
                float4 a1 = *(const float4*)(&As[kk][r0 + 4]);
                float4 w0 = *(const float4*)(&Wt[kk][c0]);
                float4 w1 = *(const float4*)(&Wt[kk][c0 + 4]);
                float a[8] = {a0.x, a0.y, a0.z, a0.w, a1.x, a1.y, a1.z, a1.w};
                float w[8] = {w0.x, w0.y, w0.z, w0.w, w1.x, w1.y, w1.z, w1.w};
#pragma unroll
                for (int i = 0; i < 8; i++)
#pragma unroll
                    for (int j = 0; j < 8; j++) acc[i][j] += a[i] * w[j];
            }
            __syncthreads();
        }
    }
    // epilogue: bias + relu + store
#pragma unroll
    for (int i = 0; i < 8; i++) {
        int grow = row0 + r0 + i;
        if (grow < M) {
#pragma unroll
            for (int j = 0; j < 8; j++) {
                float v = acc[i][j] + bias[c0 + j];
                out[(size_t)grow * DIM + c0 + j] = v > 0.f ? v : 0.f;
            }
        }
    }
}

// ---------------- graph pooling + classifier head ----------------

__global__ void pool_kernel(const float* __restrict__ h, const int* __restrict__ gid,
                            float* __restrict__ gsum, float* __restrict__ gcnt, int n) {
    int d = threadIdx.x & 127;
    int nsub = threadIdx.x >> 7;  // 2 nodes per 256-thread block-iter
    int stride = gridDim.x * 2;
    for (int i = blockIdx.x * 2 + nsub; i < n; i += stride) {
        int g = gid[i];
        atomicAdd(&gsum[(size_t)g * DIM + d], h[(size_t)i * DIM + d]);
        if (d == 0) atomicAdd(&gcnt[g], 1.0f);
    }
}

__global__ void head_kernel(const float* __restrict__ gsum, const float* __restrict__ gcnt,
                            const float* __restrict__ Wc, const float* __restrict__ bc,
                            float* __restrict__ out) {
    __shared__ float v[DIM];
    int g = blockIdx.x;
    int t = threadIdx.x;
    float c = gcnt[g];
    c = c < 1.f ? 1.f : c;
    v[t] = gsum[(size_t)g * DIM + t] / c;
    __syncthreads();
    if (t < CLASSES) {
        float acc = bc[t];
#pragma unroll 16
        for (int d = 0; d < DIM; ++d) acc += v[d] * Wc[d * CLASSES + t];
        out[g * CLASSES + t] = acc;
    }
}

// ---------------- launch ----------------

extern "C" void kernel_launch(void* const* d_in, const int* in_sizes, int n_in,
                              void* d_out, int out_size, void* d_ws, size_t ws_size,
                              hipStream_t stream) {
    const float* x   = (const float*)d_in[0];
    const int*   src = (const int*)d_in[1];
    const int*   dst = (const int*)d_in[2];
    const int*   gid = (const int*)d_in[3];
    const float* W0  = (const float*)d_in[4];
    const float* b0  = (const float*)d_in[5];
    const float* W1  = (const float*)d_in[6];
    const float* b1  = (const float*)d_in[7];
    const float* W2  = (const float*)d_in[8];
    const float* b2  = (const float*)d_in[9];
    const float* Wc  = (const float*)d_in[10];
    const float* bc  = (const float*)d_in[11];
    float* out = (float*)d_out;

    // workspace layout (floats): nrm[N] | h[N*D] | f1[N*D] | f2[N*D] | gsum[G*D] | gcnt[G]
    float* nrm  = (float*)d_ws;
    float* h    = nrm + NN;
    float* f1   = h + (size_t)NN * DIM;
    float* f2   = f1 + (size_t)NN * DIM;
    float* gsum = f2 + (size_t)NN * DIM;
    float* gcnt = gsum + (size_t)NG * DIM;

    const int nv4 = NN * DIM / 4;

    // degree -> norm
    zero_kernel<<<64, 256, 0, stream>>>(nrm, NN / 4);
    deg_kernel<<<1024, 256, 0, stream>>>(dst, nrm, NE);
    norm_kernel<<<(NN + 255) / 256, 256, 0, stream>>>(nrm, NN);

    const float* Ws_[3] = {W0, W1, W2};
    const float* bs_[3] = {b0, b1, b2};
    const float* featIn = x;
    for (int l = 0; l < 3; ++l) {
        zero_kernel<<<2048, 256, 0, stream>>>(f1, nv4);
        hop_kernel<<<4096, 256, 0, stream>>>(featIn, nrm, src, dst, f1, NE);
        scale_kernel<<<2048, 256, 0, stream>>>(f1, nrm, nv4);
        zero_kernel<<<2048, 256, 0, stream>>>(f2, nv4);
        hop_kernel<<<4096, 256, 0, stream>>>(f1, nrm, src, dst, f2, NE);
        scale_kernel<<<2048, 256, 0, stream>>>(f2, nrm, nv4);
        gemm_kernel<<<(NN + BM - 1) / BM, 256, 0, stream>>>(featIn, f1, f2, Ws_[l], bs_[l], h, NN);
        featIn = h;
    }

    // pooling (gsum and gcnt are contiguous -> one zero)
    zero_kernel<<<32, 256, 0, stream>>>(gsum, (NG * DIM + NG) / 4);
    pool_kernel<<<2048, 256, 0, stream>>>(h, gid, gsum, gcnt, NN);
    head_kernel<<<NG, DIM, 0, stream>>>(gsum, gcnt, Wc, bc, out);
}

// Round 2
// 1138.578 us; speedup vs baseline: 7.6725x; 7.6725x over previous
//
#include <hip/hip_runtime.h>
#include <math.h>

#define NN 50000
#define NE 800000
#define NG 128
#define DIM 128
#define CLASSES 10

// ---------------- CSR build ----------------

__global__ void zero_int_kernel(int* __restrict__ p, int n) {
    int i = blockIdx.x * blockDim.x + threadIdx.x;
    int stride = gridDim.x * blockDim.x;
    for (; i < n; i += stride) p[i] = 0;
}

__global__ void count_kernel(const int* __restrict__ dst, int* __restrict__ cnt, int E) {
    int i = blockIdx.x * blockDim.x + threadIdx.x;
    int stride = gridDim.x * blockDim.x;
    for (; i < E; i += stride) atomicAdd(&cnt[dst[i]], 1);
}

__global__ void norm_from_cnt_kernel(const int* __restrict__ cnt, float* __restrict__ nrm, int n) {
    int i = blockIdx.x * blockDim.x + threadIdx.x;
    if (i < n) {
        float v = (float)cnt[i];
        v = v < 1.f ? 1.f : v;
        nrm[i] = 1.0f / sqrtf(v);
    }
}

// single-block exclusive scan: rowptr[0]=0, rowptr[i+1]=sum(cnt[0..i])
__global__ __launch_bounds__(1024) void scan_kernel(const int* __restrict__ cnt,
                                                    int* __restrict__ rowptr, int n) {
    __shared__ int tile[1024];
    __shared__ int base;
    int t = threadIdx.x;
    if (t == 0) { base = 0; rowptr[0] = 0; }
    __syncthreads();
    for (int start = 0; start < n; start += 1024) {
        int i = start + t;
        tile[t] = (i < n) ? cnt[i] : 0;
        __syncthreads();
        for (int off = 1; off < 1024; off <<= 1) {
            int add = (t >= off) ? tile[t - off] : 0;
            __syncthreads();
            tile[t] += add;
            __syncthreads();
        }
        if (i < n) rowptr[i + 1] = base + tile[t];
        __syncthreads();
        if (t == 0) base += tile[1023];
        __syncthreads();
    }
}

__global__ void copy_int_kernel(const int* __restrict__ a, int* __restrict__ b, int n) {
    int i = blockIdx.x * blockDim.x + threadIdx.x;
    int stride = gridDim.x * blockDim.x;
    for (; i < n; i += stride) b[i] = a[i];
}

__global__ void fill_kernel(const int* __restrict__ src, const int* __restrict__ dst,
                            int* __restrict__ rowcur, int* __restrict__ esrc, int E) {
    int i = blockIdx.x * blockDim.x + threadIdx.x;
    int stride = gridDim.x * blockDim.x;
    for (; i < E; i += stride) {
        int pos = atomicAdd(&rowcur[dst[i]], 1);
        esrc[pos] = src[i];
    }
}

// ---------------- propagation hop (CSR gather, fused dst-norm) ----------------
// out[i] = nrm[i] * sum_{e: dst=i} feat[src]*nrm[src]
// one wave per node, float2 per lane (64*8B = 512B coalesced row reads)

__global__ __launch_bounds__(256) void gather_hop_kernel(
    const float* __restrict__ feat, const float* __restrict__ nrm,
    const int* __restrict__ rowptr, const int* __restrict__ esrc,
    float* __restrict__ out, int n) {
    int wid = (blockIdx.x * blockDim.x + threadIdx.x) >> 6;  // node id
    int lane = threadIdx.x & 63;
    if (wid >= n) return;
    int beg = rowptr[wid], end = rowptr[wid + 1];
    float ax = 0.f, ay = 0.f;
    for (int e = beg; e < end; ++e) {
        int s = esrc[e];
        float ns = nrm[s];
        float2 v = ((const float2*)(feat + (size_t)s * DIM))[lane];
        ax += v.x * ns;
        ay += v.y * ns;
    }
    float nd = nrm[wid];
    ((float2*)(out + (size_t)wid * DIM))[lane] = make_float2(ax * nd, ay * nd);
}

// ---------------- fp32 GEMM: out[M,128] = relu([A0|A1|A2] @ W + b) ----------------
// block tile 128x128, 256 threads, per-thread 8x8, BK=32; in-place (out==A0) safe:
// each block reads only its own 128 rows and writes them in the epilogue.

#define BM 128
#define BK 32

__global__ __launch_bounds__(256) void gemm_kernel(
    const float* __restrict__ A0, const float* __restrict__ A1, const float* __restrict__ A2,
    const float* __restrict__ W, const float* __restrict__ bias,
    float* __restrict__ out, int M) {
    __shared__ float As[BK][BM + 4];
    __shared__ float Wt[BK][DIM];

    int tid = threadIdx.x;
    int row0 = blockIdx.x * BM;
    int r0 = (tid >> 4) * 8;
    int c0 = (tid & 15) * 8;

    float acc[8][8];
#pragma unroll
    for (int i = 0; i < 8; i++)
#pragma unroll
        for (int j = 0; j < 8; j++) acc[i][j] = 0.f;

    const float* parts[3] = {A0, A1, A2};
    for (int p = 0; p < 3; ++p) {
        const float* A = parts[p];
        for (int kc = 0; kc < DIM; kc += BK) {
#pragma unroll
            for (int it = 0; it < 4; ++it) {
                int r = (tid >> 3) + 32 * it;
                int k4 = (tid & 7) * 4;
                int grow = row0 + r;
                float4 v = make_float4(0.f, 0.f, 0.f, 0.f);
                if (grow < M) v = *(const float4*)(A + (size_t)grow * DIM + kc + k4);
                As[k4 + 0][r] = v.x;
                As[k4 + 1][r] = v.y;
                As[k4 + 2][r] = v.z;
                As[k4 + 3][r] = v.w;
            }
#pragma unroll
            for (int it = 0; it < 4; ++it) {
                int k = (tid >> 5) + 8 * it;
                int c = (tid & 31) * 4;
                *(float4*)(&Wt[k][c]) = *(const float4*)(W + (size_t)(p * DIM + kc + k) * DIM + c);
            }
            __syncthreads();
#pragma unroll
            for (int kk = 0; kk < BK; ++kk) {
                float4 a0 = *(const float4*)(&As[kk][r0]);
                float4 a1 = *(const float4*)(&As[kk][r0 + 4]);
                float4 w0 = *(const float4*)(&Wt[kk][c0]);
                float4 w1 = *(const float4*)(&Wt[kk][c0 + 4]);
                float a[8] = {a0.x, a0.y, a0.z, a0.w, a1.x, a1.y, a1.z, a1.w};
                float w[8] = {w0.x, w0.y, w0.z, w0.w, w1.x, w1.y, w1.z, w1.w};
#pragma unroll
                for (int i = 0; i < 8; i++)
#pragma unroll
                    for (int j = 0; j < 8; j++) acc[i][j] += a[i] * w[j];
            }
            __syncthreads();
        }
    }
#pragma unroll
    for (int i = 0; i < 8; i++) {
        int grow = row0 + r0 + i;
        if (grow < M) {
#pragma unroll
            for (int j = 0; j < 8; j++) {
                float v = acc[i][j] + bias[c0 + j];
                out[(size_t)grow * DIM + c0 + j] = v > 0.f ? v : 0.f;
            }
        }
    }
}

// ---------------- fused mean-pool + classifier head ----------------
// graph_ids is SORTED: block g binary-searches its node range, segment-reduces,
// then 10 threads compute the class logits. No atomics, no gsum buffer.

__global__ __launch_bounds__(128) void pool_head_kernel(
    const float* __restrict__ h, const int* __restrict__ gid,
    const float* __restrict__ Wc, const float* __restrict__ bc,
    float* __restrict__ out) {
    __shared__ float v[DIM];
    __shared__ int sbeg, send;
    int g = blockIdx.x;
    int t = threadIdx.x;
    if (t == 0) {
        int lo = 0, hi = NN;
        while (lo < hi) { int m = (lo + hi) >> 1; if (gid[m] < g) lo = m + 1; else hi = m; }
        sbeg = lo;
    }
    if (t == 1 || (blockDim.x == 1 && t == 0)) {
        int lo = 0, hi = NN;
        while (lo < hi) { int m = (lo + hi) >> 1; if (gid[m] < g + 1) lo = m + 1; else hi = m; }
        send = lo;
    }
    __syncthreads();
    int beg = sbeg, end = send;
    float acc = 0.f;
    for (int i = beg; i < end; ++i) acc += h[(size_t)i * DIM + t];
    float c = (float)(end - beg);
    c = c < 1.f ? 1.f : c;
    v[t] = acc / c;
    __syncthreads();
    if (t < CLASSES) {
        float o = bc[t];
#pragma unroll 16
        for (int d = 0; d < DIM; ++d) o += v[d] * Wc[d * CLASSES + t];
        out[g * CLASSES + t] = o;
    }
}

// ---------------- launch ----------------

extern "C" void kernel_launch(void* const* d_in, const int* in_sizes, int n_in,
                              void* d_out, int out_size, void* d_ws, size_t ws_size,
                              hipStream_t stream) {
    const float* x   = (const float*)d_in[0];
    const int*   src = (const int*)d_in[1];
    const int*   dst = (const int*)d_in[2];
    const int*   gid = (const int*)d_in[3];
    const float* W0  = (const float*)d_in[4];
    const float* b0  = (const float*)d_in[5];
    const float* W1  = (const float*)d_in[6];
    const float* b1  = (const float*)d_in[7];
    const float* W2  = (const float*)d_in[8];
    const float* b2  = (const float*)d_in[9];
    const float* Wc  = (const float*)d_in[10];
    const float* bc  = (const float*)d_in[11];
    float* out = (float*)d_out;

    // workspace layout:
    // floats: nrm[N] | h[N*D] | f1[N*D] | f2[N*D]
    // ints:   cnt[N] (reused as rowcur) | rowptr[N+1] | esrc[E]
    float* nrm = (float*)d_ws;
    float* h   = nrm + NN;
    float* f1  = h + (size_t)NN * DIM;
    float* f2  = f1 + (size_t)NN * DIM;
    int* cnt    = (int*)(f2 + (size_t)NN * DIM);
    int* rowptr = cnt + NN;
    int* esrc   = rowptr + NN + 1;

    // CSR build (amortized over 6 hops)
    zero_int_kernel<<<64, 256, 0, stream>>>(cnt, NN);
    count_kernel<<<1024, 256, 0, stream>>>(dst, cnt, NE);
    norm_from_cnt_kernel<<<(NN + 255) / 256, 256, 0, stream>>>(cnt, nrm, NN);
    scan_kernel<<<1, 1024, 0, stream>>>(cnt, rowptr, NN);
    copy_int_kernel<<<64, 256, 0, stream>>>(rowptr, cnt, NN);  // cnt becomes rowcur
    fill_kernel<<<1024, 256, 0, stream>>>(src, dst, cnt, esrc, NE);

    const float* Ws_[3] = {W0, W1, W2};
    const float* bs_[3] = {b0, b1, b2};
    const float* featIn = x;
    const int hop_blocks = (NN * 64 + 255) / 256;
    for (int l = 0; l < 3; ++l) {
        gather_hop_kernel<<<hop_blocks, 256, 0, stream>>>(featIn, nrm, rowptr, esrc, f1, NN);
        gather_hop_kernel<<<hop_blocks, 256, 0, stream>>>(f1, nrm, rowptr, esrc, f2, NN);
        gemm_kernel<<<(NN + BM - 1) / BM, 256, 0, stream>>>(featIn, f1, f2, Ws_[l], bs_[l], h, NN);
        featIn = h;
    }

    pool_head_kernel<<<NG, DIM, 0, stream>>>(h, gid, Wc, bc, out);
}

// Round 3
// 868.291 us; speedup vs baseline: 10.0608x; 1.3113x over previous
//
#include <hip/hip_runtime.h>
#include <math.h>

#define NN 50000
#define NE 800000
#define NG 128
#define DIM 128
#define CLASSES 10

// ---------------- utility ----------------

__global__ void zero_kernel(float* __restrict__ p, int n4) {
    int i = blockIdx.x * blockDim.x + threadIdx.x;
    int stride = gridDim.x * blockDim.x;
    float4 z = make_float4(0.f, 0.f, 0.f, 0.f);
    for (; i < n4; i += stride) ((float4*)p)[i] = z;
}

__global__ void zero_int_kernel(int* __restrict__ p, int n) {
    int i = blockIdx.x * blockDim.x + threadIdx.x;
    int stride = gridDim.x * blockDim.x;
    for (; i < n; i += stride) p[i] = 0;
}

// ---------------- CSR build ----------------

__global__ void count_kernel(const int* __restrict__ dst, int* __restrict__ cnt, int E) {
    int i = blockIdx.x * blockDim.x + threadIdx.x;
    int stride = gridDim.x * blockDim.x;
    for (; i < E; i += stride) atomicAdd(&cnt[dst[i]], 1);
}

__global__ void norm_from_cnt_kernel(const int* __restrict__ cnt, float* __restrict__ nrm, int n) {
    int i = blockIdx.x * blockDim.x + threadIdx.x;
    if (i < n) {
        float v = (float)cnt[i];
        v = v < 1.f ? 1.f : v;
        nrm[i] = 1.0f / sqrtf(v);
    }
}

// single-block exclusive scan via wave shuffles: rowptr[0]=0, rowptr[i+1]=incl_sum(cnt[0..i])
__global__ __launch_bounds__(1024) void scan_kernel(const int* __restrict__ cnt,
                                                    int* __restrict__ rowptr, int n) {
    __shared__ int wsum[16];
    __shared__ int base;
    int t = threadIdx.x;
    int lane = t & 63, wv = t >> 6;
    if (t == 0) { base = 0; rowptr[0] = 0; }
    __syncthreads();
    for (int start = 0; start < n; start += 1024) {
        int i = start + t;
        int v = (i < n) ? cnt[i] : 0;
#pragma unroll
        for (int off = 1; off < 64; off <<= 1) {
            int u = __shfl_up(v, off);
            if (lane >= off) v += u;
        }
        if (lane == 63) wsum[wv] = v;
        __syncthreads();
        if (wv == 0) {
            int s = (lane < 16) ? wsum[lane] : 0;
#pragma unroll
            for (int off = 1; off < 16; off <<= 1) {
                int u = __shfl_up(s, off);
                if (lane >= off) s += u;
            }
            if (lane < 16) wsum[lane] = s;
        }
        __syncthreads();
        int woff = (wv > 0) ? wsum[wv - 1] : 0;
        if (i < n) rowptr[i + 1] = base + woff + v;
        __syncthreads();
        if (t == 0) base += wsum[15];
        __syncthreads();
    }
}

__global__ void copy_int_kernel(const int* __restrict__ a, int* __restrict__ b, int n) {
    int i = blockIdx.x * blockDim.x + threadIdx.x;
    int stride = gridDim.x * blockDim.x;
    for (; i < n; i += stride) b[i] = a[i];
}

__global__ void fill_kernel(const int* __restrict__ src, const int* __restrict__ dst,
                            int* __restrict__ rowcur, int* __restrict__ esrc, int E) {
    int i = blockIdx.x * blockDim.x + threadIdx.x;
    int stride = gridDim.x * blockDim.x;
    for (; i < E; i += stride) {
        int pos = atomicAdd(&rowcur[dst[i]], 1);
        esrc[pos] = src[i];
    }
}

// ---------------- propagation hop (CSR gather, batched + shfl broadcast) ----------------
// out[i] = nrm[i] * sum_{e: dst=i} feat[src]*nrm[src]
// one wave per node. Per 64-edge batch: lane loads esrc (coalesced) + nrm[s] (L2-hit gather),
// then shfl-broadcasts (s,w) per edge; feat-row gathers unrolled x4 for ILP.

__global__ __launch_bounds__(256) void gather_hop_kernel(
    const float* __restrict__ feat, const float* __restrict__ nrm,
    const int* __restrict__ rowptr, const int* __restrict__ esrc,
    float* __restrict__ out, int n) {
    int wid = (blockIdx.x * blockDim.x + threadIdx.x) >> 6;
    int lane = threadIdx.x & 63;
    if (wid >= n) return;
    int beg = rowptr[wid], end = rowptr[wid + 1];
    int deg = end - beg;
    float ax = 0.f, ay = 0.f;
    for (int b = 0; b < deg; b += 64) {
        int rem = deg - b; if (rem > 64) rem = 64;
        int sE = 0; float wE = 0.f;
        if (lane < rem) {
            sE = esrc[beg + b + lane];
            wE = nrm[sE];
        }
        int k = 0;
        for (; k + 3 < rem; k += 4) {
            int s0 = __shfl(sE, k),     s1 = __shfl(sE, k + 1);
            int s2 = __shfl(sE, k + 2), s3 = __shfl(sE, k + 3);
            float w0 = __shfl(wE, k),     w1 = __shfl(wE, k + 1);
            float w2 = __shfl(wE, k + 2), w3 = __shfl(wE, k + 3);
            float2 v0 = ((const float2*)(feat + (size_t)s0 * DIM))[lane];
            float2 v1 = ((const float2*)(feat + (size_t)s1 * DIM))[lane];
            float2 v2 = ((const float2*)(feat + (size_t)s2 * DIM))[lane];
            float2 v3 = ((const float2*)(feat + (size_t)s3 * DIM))[lane];
            ax += v0.x * w0 + v1.x * w1 + v2.x * w2 + v3.x * w3;
            ay += v0.y * w0 + v1.y * w1 + v2.y * w2 + v3.y * w3;
        }
        for (; k < rem; ++k) {
            int s = __shfl(sE, k);
            float w = __shfl(wE, k);
            float2 v = ((const float2*)(feat + (size_t)s * DIM))[lane];
            ax += v.x * w;
            ay += v.y * w;
        }
    }
    float nd = nrm[wid];
    ((float2*)(out + (size_t)wid * DIM))[lane] = make_float2(ax * nd, ay * nd);
}

// ---------------- fp32 GEMM: out[M,128] = relu([A0|A1|A2] @ W + b) ----------------

#define BM 128
#define BK 32

__global__ __launch_bounds__(256) void gemm_kernel(
    const float* __restrict__ A0, const float* __restrict__ A1, const float* __restrict__ A2,
    const float* __restrict__ W, const float* __restrict__ bias,
    float* __restrict__ out, int M) {
    __shared__ float As[BK][BM + 4];
    __shared__ float Wt[BK][DIM];

    int tid = threadIdx.x;
    int row0 = blockIdx.x * BM;
    int r0 = (tid >> 4) * 8;
    int c0 = (tid & 15) * 8;

    float acc[8][8];
#pragma unroll
    for (int i = 0; i < 8; i++)
#pragma unroll
        for (int j = 0; j < 8; j++) acc[i][j] = 0.f;

    const float* parts[3] = {A0, A1, A2};
    for (int p = 0; p < 3; ++p) {
        const float* A = parts[p];
        for (int kc = 0; kc < DIM; kc += BK) {
#pragma unroll
            for (int it = 0; it < 4; ++it) {
                int r = (tid >> 3) + 32 * it;
                int k4 = (tid & 7) * 4;
                int grow = row0 + r;
                float4 v = make_float4(0.f, 0.f, 0.f, 0.f);
                if (grow < M) v = *(const float4*)(A + (size_t)grow * DIM + kc + k4);
                As[k4 + 0][r] = v.x;
                As[k4 + 1][r] = v.y;
                As[k4 + 2][r] = v.z;
                As[k4 + 3][r] = v.w;
            }
#pragma unroll
            for (int it = 0; it < 4; ++it) {
                int k = (tid >> 5) + 8 * it;
                int c = (tid & 31) * 4;
                *(float4*)(&Wt[k][c]) = *(const float4*)(W + (size_t)(p * DIM + kc + k) * DIM + c);
            }
            __syncthreads();
#pragma unroll
            for (int kk = 0; kk < BK; ++kk) {
                float4 a0 = *(const float4*)(&As[kk][r0]);
                float4 a1 = *(const float4*)(&As[kk][r0 + 4]);
                float4 w0 = *(const float4*)(&Wt[kk][c0]);
                float4 w1 = *(const float4*)(&Wt[kk][c0 + 4]);
                float a[8] = {a0.x, a0.y, a0.z, a0.w, a1.x, a1.y, a1.z, a1.w};
                float w[8] = {w0.x, w0.y, w0.z, w0.w, w1.x, w1.y, w1.z, w1.w};
#pragma unroll
                for (int i = 0; i < 8; i++)
#pragma unroll
                    for (int j = 0; j < 8; j++) acc[i][j] += a[i] * w[j];
            }
            __syncthreads();
        }
    }
#pragma unroll
    for (int i = 0; i < 8; i++) {
        int grow = row0 + r0 + i;
        if (grow < M) {
#pragma unroll
            for (int j = 0; j < 8; j++) {
                float v = acc[i][j] + bias[c0 + j];
                out[(size_t)grow * DIM + c0 + j] = v > 0.f ? v : 0.f;
            }
        }
    }
}

// ---------------- pooling: parallel partial sums (sorted gid, run-length + atomics) ----------------

#define PCHUNK 64

__global__ __launch_bounds__(128) void pool_partial_kernel(
    const float* __restrict__ h, const int* __restrict__ gid,
    float* __restrict__ gsum, int n) {
    int d = threadIdx.x;
    int i0 = blockIdx.x * PCHUNK;
    if (i0 >= n) return;
    int i1 = i0 + PCHUNK; if (i1 > n) i1 = n;
    int curg = gid[i0];
    float acc = 0.f;
    for (int i = i0; i < i1; ++i) {
        int g = gid[i];
        if (g != curg) {
            atomicAdd(&gsum[(size_t)curg * DIM + d], acc);
            acc = 0.f;
            curg = g;
        }
        acc += h[(size_t)i * DIM + d];
    }
    atomicAdd(&gsum[(size_t)curg * DIM + d], acc);
}

__global__ __launch_bounds__(128) void head_kernel(
    const float* __restrict__ gsum, const int* __restrict__ gid,
    const float* __restrict__ Wc, const float* __restrict__ bc,
    float* __restrict__ out) {
    __shared__ float v[DIM];
    __shared__ int sbeg, send;
    int g = blockIdx.x;
    int t = threadIdx.x;
    if (t == 0) {
        int lo = 0, hi = NN;
        while (lo < hi) { int m = (lo + hi) >> 1; if (gid[m] < g) lo = m + 1; else hi = m; }
        sbeg = lo;
    }
    if (t == 1) {
        int lo = 0, hi = NN;
        while (lo < hi) { int m = (lo + hi) >> 1; if (gid[m] < g + 1) lo = m + 1; else hi = m; }
        send = lo;
    }
    __syncthreads();
    float c = (float)(send - sbeg);
    c = c < 1.f ? 1.f : c;
    v[t] = gsum[(size_t)g * DIM + t] / c;
    __syncthreads();
    if (t < CLASSES) {
        float o = bc[t];
#pragma unroll 16
        for (int d = 0; d < DIM; ++d) o += v[d] * Wc[d * CLASSES + t];
        out[g * CLASSES + t] = o;
    }
}

// ---------------- launch ----------------

extern "C" void kernel_launch(void* const* d_in, const int* in_sizes, int n_in,
                              void* d_out, int out_size, void* d_ws, size_t ws_size,
                              hipStream_t stream) {
    const float* x   = (const float*)d_in[0];
    const int*   src = (const int*)d_in[1];
    const int*   dst = (const int*)d_in[2];
    const int*   gid = (const int*)d_in[3];
    const float* W0  = (const float*)d_in[4];
    const float* b0  = (const float*)d_in[5];
    const float* W1  = (const float*)d_in[6];
    const float* b1  = (const float*)d_in[7];
    const float* W2  = (const float*)d_in[8];
    const float* b2  = (const float*)d_in[9];
    const float* Wc  = (const float*)d_in[10];
    const float* bc  = (const float*)d_in[11];
    float* out = (float*)d_out;

    // workspace: floats nrm[N] | h[N*D] | f1[N*D] | f2[N*D] | gsum[G*D]
    //            ints   cnt[N] | rowptr[N+1] | esrc[E]
    float* nrm  = (float*)d_ws;
    float* h    = nrm + NN;
    float* f1   = h + (size_t)NN * DIM;
    float* f2   = f1 + (size_t)NN * DIM;
    float* gsum = f2 + (size_t)NN * DIM;
    int* cnt    = (int*)(gsum + (size_t)NG * DIM);
    int* rowptr = cnt + NN;
    int* esrc   = rowptr + NN + 1;

    // CSR build (amortized over 6 hops)
    zero_int_kernel<<<64, 256, 0, stream>>>(cnt, NN);
    count_kernel<<<1024, 256, 0, stream>>>(dst, cnt, NE);
    norm_from_cnt_kernel<<<(NN + 255) / 256, 256, 0, stream>>>(cnt, nrm, NN);
    scan_kernel<<<1, 1024, 0, stream>>>(cnt, rowptr, NN);
    copy_int_kernel<<<64, 256, 0, stream>>>(rowptr, cnt, NN);  // cnt becomes rowcur
    fill_kernel<<<1024, 256, 0, stream>>>(src, dst, cnt, esrc, NE);

    const float* Ws_[3] = {W0, W1, W2};
    const float* bs_[3] = {b0, b1, b2};
    const float* featIn = x;
    const int hop_blocks = (NN * 64 + 255) / 256;
    for (int l = 0; l < 3; ++l) {
        gather_hop_kernel<<<hop_blocks, 256, 0, stream>>>(featIn, nrm, rowptr, esrc, f1, NN);
        gather_hop_kernel<<<hop_blocks, 256, 0, stream>>>(f1, nrm, rowptr, esrc, f2, NN);
        gemm_kernel<<<(NN + BM - 1) / BM, 256, 0, stream>>>(featIn, f1, f2, Ws_[l], bs_[l], h, NN);
        featIn = h;
    }

    // pooling + head
    zero_kernel<<<16, 256, 0, stream>>>(gsum, NG * DIM / 4);
    pool_partial_kernel<<<(NN + PCHUNK - 1) / PCHUNK, 128, 0, stream>>>(h, gid, gsum, NN);
    head_kernel<<<NG, DIM, 0, stream>>>(gsum, gid, Wc, bc, out);
}